// Round 15
// baseline (155.042 us; speedup 1.0000x reference)
//
#include <hip/hip_runtime.h>

#define HDIM 512
#define HALF 256
#define NRELS 12
#define NBASES 8
#define NLAYERS 12
#define NBLOCKS 2
#define NHEADS 8
#define NENTS 50000
#define TXTD 768
#define BATCH 32
#define ELEN 50
#define SLEN 128
#define NPOS (BATCH * ELEN)   // 1600
#define NSEG (NPOS * NRELS)   // 19200
#define BCAP 64

typedef unsigned short u16;
typedef __attribute__((ext_vector_type(8))) __bf16 bf16x8;
typedef __attribute__((ext_vector_type(4))) float f32x4;

__device__ __forceinline__ u16 f2bf(float f) {
    unsigned int u = __float_as_uint(f);
    unsigned int r = (u + 0x7FFFu + ((u >> 16) & 1u)) >> 16;
    return (u16)r;
}
__device__ __forceinline__ float bf2f(u16 v) {
    return __uint_as_float(((unsigned int)v) << 16);
}

#define ASYNC_COPY16(g, l)                                                              \
    __builtin_amdgcn_global_load_lds((const __attribute__((address_space(1))) void*)(g), \
                                     (__attribute__((address_space(3))) unsigned int*)(l), 16, 0, 0)

// ---------------------------------------------------------------------------
// 0) init: blk0 = map-clear + CAS-dedup (owns map/uniq/nuniq exclusively);
//    blk1-2 = biasC; blk3-130 = segcnt/ZB/SW zeroing.
// ---------------------------------------------------------------------------
__global__ void init_kernel(const int* __restrict__ eid,
                            int* __restrict__ map, int* __restrict__ uniq,
                            int* __restrict__ nuniq, int* __restrict__ segcnt,
                            float* __restrict__ zb,
                            const float* __restrict__ kgb, const float* __restrict__ imb,
                            const float* __restrict__ txb, u16* __restrict__ SW,
                            const float* __restrict__ rgcn_bias,
                            const float* __restrict__ kg_proj_w,
                            const float* __restrict__ kg_proj_b,
                            float* __restrict__ biasC, float* __restrict__ out_last) {
    int blk = blockIdx.x;
    int t = threadIdx.x;
    if (blk == 0) {
        // exclusive owner of map / uniq / nuniq
        int4 m4 = {-1, -1, -1, -1};
        for (int i = t; i < NENTS / 4; i += 256) ((int4*)map)[i] = m4;
        if (t == 0) { *nuniq = 0; *out_last = 0.f; }
        __syncthreads();   // orders this block's global writes for this block
        for (int i = t; i < NPOS; i += 256) {
            int n = eid[i];
            int old = atomicCAS(&map[n], -1, -2);
            if (old == -1) {
                int idx = atomicAdd(nuniq, 1);
                uniq[idx] = n;
                __threadfence();
                map[n] = idx;
            }
        }
        return;
    }
    if (blk <= 2) {
        int n = (blk - 1) * 256 + t;
        float acc = kg_proj_b[n];
        for (int c = 0; c < HALF; ++c) acc += rgcn_bias[c] * kg_proj_w[(size_t)c * HDIM + n];
        biasC[n] = acc;
        return;
    }
    int tid = (blk - 3) * 256 + t;
    const int nt = 128 * 256;
    int4 z4 = {0, 0, 0, 0};
    for (int i = tid; i < NSEG / 4; i += nt) ((int4*)segcnt)[i] = z4;
    for (int i = tid; i < 2304; i += nt) zb[i] = 0.f;
    if (tid < HDIM) {
        SW[(size_t)1536 * HDIM + tid] = f2bf(kgb[tid]);
        SW[(size_t)1537 * HDIM + tid] = f2bf(imb[tid]);
        SW[(size_t)1538 * HDIM + tid] = f2bf(txb[tid]);
    }
}

// ---------------------------------------------------------------------------
// 1) midprep: {tokmean(64) | gather(288) | edge ILP4(512) | prep(3232)} = 4096
// ---------------------------------------------------------------------------
struct PrepArgs {
    const float* src[12];
    u16* dst[12];
};

__global__ __launch_bounds__(256) void midprep_kernel(
    const float* __restrict__ tok, u16* __restrict__ TMEAN,
    const int* __restrict__ uniq, const int* __restrict__ nuniq,
    const float* __restrict__ txi, const float* __restrict__ imi,
    u16* __restrict__ TXIN, u16* __restrict__ IMIN,
    const int* __restrict__ ei, const int* __restrict__ et, const int* __restrict__ map,
    int* __restrict__ segcnt, int* __restrict__ bucket, int E, PrepArgs a) {
    int blk = blockIdx.x;
    int t = threadIdx.x;
    if (blk < 64) {
        // tokmean
        int b = blk >> 1;
        int col = (blk & 1) * 256 + t;
        float s = 0.f;
        for (int si = 0; si < SLEN; ++si) s += tok[((size_t)b * SLEN + si) * HDIM + col];
        TMEAN[(size_t)b * HDIM + col] = f2bf(s * (1.0f / SLEN));
    } else if (blk < 352) {
        // gather text/image rows
        if (t >= TXTD / 4) return;
        int nu = *nuniq;
        for (int u = blk - 64; u < NPOS; u += 288) {
            if (u >= nu) {
                ushort4 z = {0, 0, 0, 0};
                ((ushort4*)(TXIN + (size_t)u * TXTD))[t] = z;
                ((ushort4*)(IMIN + (size_t)u * TXTD))[t] = z;
                continue;
            }
            int n = uniq[u];
            float4 v = ((const float4*)(txi + (size_t)n * TXTD))[t];
            ushort4 o;
            o.x = f2bf(v.x); o.y = f2bf(v.y); o.z = f2bf(v.z); o.w = f2bf(v.w);
            ((ushort4*)(TXIN + (size_t)u * TXTD))[t] = o;
            v = ((const float4*)(imi + (size_t)n * TXTD))[t];
            o.x = f2bf(v.x); o.y = f2bf(v.y); o.z = f2bf(v.z); o.w = f2bf(v.w);
            ((ushort4*)(IMIN + (size_t)u * TXTD))[t] = o;
        }
    } else if (blk < 864) {
        // edge filter, 4 edges/thread via int4 (independent probe chains)
        const int* __restrict__ dstA = ei + E;
        int gtid = (blk - 352) * 256 + t;
        int e0 = gtid * 4;
        if (e0 + 3 < E) {
            int4 d4 = *(const int4*)(dstA + e0);
            int4 t4 = *(const int4*)(et + e0);
            int cc0 = map[d4.x], cc1 = map[d4.y], cc2 = map[d4.z], cc3 = map[d4.w];
            if (cc0 >= 0) {
                int seg = cc0 * NRELS + t4.x;
                int p = atomicAdd(&segcnt[seg], 1);
                if (p < BCAP) bucket[seg * BCAP + p] = ei[e0];
            }
            if (cc1 >= 0) {
                int seg = cc1 * NRELS + t4.y;
                int p = atomicAdd(&segcnt[seg], 1);
                if (p < BCAP) bucket[seg * BCAP + p] = ei[e0 + 1];
            }
            if (cc2 >= 0) {
                int seg = cc2 * NRELS + t4.z;
                int p = atomicAdd(&segcnt[seg], 1);
                if (p < BCAP) bucket[seg * BCAP + p] = ei[e0 + 2];
            }
            if (cc3 >= 0) {
                int seg = cc3 * NRELS + t4.w;
                int p = atomicAdd(&segcnt[seg], 1);
                if (p < BCAP) bucket[seg * BCAP + p] = ei[e0 + 3];
            }
        } else {
            for (int e = e0; e < E; ++e) {
                int c = map[dstA[e]];
                if (c >= 0) {
                    int seg = c * NRELS + et[e];
                    int p = atomicAdd(&segcnt[seg], 1);
                    if (p < BCAP) bucket[seg * BCAP + p] = ei[e];
                }
            }
        }
    } else {
        // weight prep: 64x64 transposes ops 0-6, straight converts ops 7-11
        // 0:kgproj 1:txproj 2:improj 3:w1 4:w2 5:pp2 6:cq | 7:basis 8:root 9,10,11:score
        constexpr int NN[7]  = {512, 512, 512, 256, 512, 12288, 512};
        constexpr int LDT[7] = {256, 768, 768, 512, 256, 512, 512};
        constexpr int BASE[13] = {0, 32, 128, 224, 256, 288, 1824,
                                  1888, 2400, 2464, 2720, 2976, 3232};
        __shared__ u16 tb[64][65];
        int bid = blk - 864;
        int op = 0;
        #pragma unroll
        for (int i = 1; i < 12; ++i)
            if (bid >= BASE[i]) op = i;
        int idx = bid - BASE[op];
        if (op < 7) {
            int Nv = 0, ldt = 0;
            #pragma unroll
            for (int i = 0; i < 7; ++i)
                if (op == i) { Nv = NN[i]; ldt = LDT[i]; }
            int ncols = Nv >> 6;
            int n0 = (idx % ncols) * 64, k0 = (idx / ncols) * 64;
            const float* W = a.src[op];
            u16* WT = a.dst[op];
            int lane = t & 63, wv = t >> 6;
            #pragma unroll
            for (int i2 = 0; i2 < 16; ++i2) {
                int r = wv * 16 + i2;
                tb[r][lane] = f2bf(W[(size_t)(k0 + r) * Nv + n0 + lane]);
            }
            __syncthreads();
            #pragma unroll
            for (int i2 = 0; i2 < 16; ++i2) {
                int rr = wv * 16 + i2;
                WT[(size_t)(n0 + rr) * ldt + k0 + lane] = tb[lane][rr];
            }
        } else {
            int e = idx * 1024 + t * 4;
            float4 v = *(const float4*)(a.src[op] + e);
            ushort4 o;
            o.x = f2bf(v.x); o.y = f2bf(v.y); o.z = f2bf(v.z); o.w = f2bf(v.w);
            *(ushort4*)(a.dst[op] + e) = o;
        }
    }
}

// ---------------------------------------------------------------------------
// MFMA bf16 GEMM body (outbf runtime) — 4-wave, 64x64, WM=WN=32
// ---------------------------------------------------------------------------
template <int BM, int BN, int WM, int WN, bool SCATTER>
__device__ __forceinline__ void gemm_body(const u16* __restrict__ A, const u16* __restrict__ BT,
                                          const float* __restrict__ bias,
                                          void* __restrict__ Cout, int M, int N, int K,
                                          int bx, int by, bool outbf) {
    constexpr int MF = WM / 16, NF = WN / 16;
    constexpr int NWC = BN / WN;
    __shared__ u16 ldsA[BM][64];
    __shared__ u16 ldsB[BN][64];
    const int tid = threadIdx.x;
    const int lane = tid & 63;
    const int wv = tid >> 6;
    const int m0 = by * BM;
    const int n0 = bx * BN;
    const int wr = wv / NWC, wc = wv % NWC;
    const int srow = lane >> 3;
    const int sslot = lane & 7;

    f32x4 acc[MF][NF];
    #pragma unroll
    for (int i = 0; i < MF; ++i)
        #pragma unroll
        for (int j = 0; j < NF; ++j)
            #pragma unroll
            for (int r = 0; r < 4; ++r) acc[i][j][r] = 0.f;

    for (int k0 = 0; k0 < K; k0 += 64) {
        #pragma unroll
        for (int i = 0; i < BM / 32; ++i) {
            int R = wv * (BM / 4) + i * 8 + srow;
            int gm = m0 + R;
            gm = gm < M ? gm : M - 1;
            int s = sslot ^ (R & 7);
            ASYNC_COPY16(A + (size_t)gm * K + k0 + s * 8, &ldsA[wv * (BM / 4) + i * 8][0]);
        }
        #pragma unroll
        for (int i = 0; i < BN / 32; ++i) {
            int R = wv * (BN / 4) + i * 8 + srow;
            int s = sslot ^ (R & 7);
            ASYNC_COPY16(BT + (size_t)(n0 + R) * K + k0 + s * 8, &ldsB[wv * (BN / 4) + i * 8][0]);
        }
        __syncthreads();
        #pragma unroll
        for (int ks = 0; ks < 2; ++ks) {
            bf16x8 af[MF], bf[NF];
            int kg = ks * 4 + (lane >> 4);
            int rl = lane & 15;
            #pragma unroll
            for (int i = 0; i < MF; ++i) {
                int row = wr * WM + i * 16 + rl;
                af[i] = *(const bf16x8*)&ldsA[row][(kg ^ (row & 7)) * 8];
            }
            #pragma unroll
            for (int j = 0; j < NF; ++j) {
                int row = wc * WN + j * 16 + rl;
                bf[j] = *(const bf16x8*)&ldsB[row][(kg ^ (row & 7)) * 8];
            }
            #pragma unroll
            for (int i = 0; i < MF; ++i)
                #pragma unroll
                for (int j = 0; j < NF; ++j)
                    acc[i][j] = __builtin_amdgcn_mfma_f32_16x16x32_bf16(af[i], bf[j], acc[i][j], 0, 0, 0);
        }
        __syncthreads();
    }

    const int rl = lane & 15, rg = lane >> 4;
    #pragma unroll
    for (int i = 0; i < MF; ++i) {
        #pragma unroll
        for (int j = 0; j < NF; ++j) {
            int col = n0 + wc * WN + j * 16 + rl;
            float bv = bias[col];
            #pragma unroll
            for (int r = 0; r < 4; ++r) {
                int row = m0 + wr * WM + i * 16 + rg * 4 + r;
                if (row >= M) continue;
                float x = acc[i][j][r] + bv;
                if (SCATTER) {
                    int layer = col >> 10, blk = (col >> 9) & 1, head = (col >> 6) & 7, hd = col & 63;
                    int bb = row / ELEN, ll = row - bb * ELEN;
                    size_t oi = (((((size_t)layer * NBLOCKS + blk) * BATCH + bb) * NHEADS + head) * ELEN + ll) * 64 + hd;
                    ((float*)Cout)[oi] = x;
                } else if (outbf) {
                    ((u16*)Cout)[(size_t)row * N + col] = f2bf(x);
                } else {
                    ((float*)Cout)[(size_t)row * N + col] = x;
                }
            }
        }
    }
}

// ---------------------------------------------------------------------------
// 2) build: [0,1600) MBX | [1600,1608) QB | [1608,1896) WC       (1896 blocks)
// ---------------------------------------------------------------------------
struct BuildArgs {
    const int *segcnt, *bucket, *uniq, *nuniq;
    const float *comp, *x;
    u16* MBX;
    const u16 *TMEAN, *CQT;
    const float* cq_b;
    u16* QB;
    const u16 *KGT, *W1f;
    const float* ZB;
    u16* WC;
};
__global__ __launch_bounds__(256) void build_kernel(BuildArgs a) {
    int blk = blockIdx.x;
    if (blk >= NPOS) {
        const u16 *A, *BT;
        const float* bias;
        u16* C;
        int M, N, K, bx, by;
        if (blk >= NPOS + 8) {
            int i = blk - (NPOS + 8);
            A = a.KGT; BT = a.W1f; bias = a.ZB; C = a.WC;
            M = HDIM; N = 2304; K = HALF; bx = i % 36; by = i / 36;
        } else {
            A = a.TMEAN; BT = a.CQT; bias = a.cq_b; C = a.QB;
            M = BATCH; N = HDIM; K = HDIM; bx = blk - NPOS; by = 0;
        }
        gemm_body<64, 64, 32, 32, false>(A, BT, bias, C, M, N, K, bx, by, true);
        return;
    }
    int u = blk;
    int i = threadIdx.x;
    __shared__ float sc[NRELS * NBASES];
    if (i < NRELS * NBASES) sc[i] = a.comp[i];
    __syncthreads();
    u16* row = a.MBX + (size_t)u * 2304;
    int nu = *a.nuniq;
    if (u >= nu) {
        for (int b = 0; b < NBASES + 1; ++b) row[b * HALF + i] = 0;
        return;
    }
    float mr[NRELS];
    #pragma unroll
    for (int r = 0; r < NRELS; ++r) {
        int seg = u * NRELS + r;
        int c = a.segcnt[seg];
        int n = min(c, BCAP);
        float acc = 0.f;
        for (int e = 0; e < n; ++e) {
            int s = a.bucket[seg * BCAP + e];
            acc += a.x[(size_t)s * HALF + i];
        }
        mr[r] = acc * (1.f / fmaxf((float)c, 1.f));
    }
    #pragma unroll
    for (int b = 0; b < NBASES; ++b) {
        float v = 0.f;
        #pragma unroll
        for (int r = 0; r < NRELS; ++r) v += sc[r * NBASES + b] * mr[r];
        row[b * HALF + i] = f2bf(v);
    }
    row[NBASES * HALF + i] = f2bf(a.x[(size_t)a.uniq[u] * HALF + i]);
}

// ---------------------------------------------------------------------------
// 3) proj: {KGU(200) | QP(25) | TXU(200) | IMU(200)} = 625 blocks
// ---------------------------------------------------------------------------
struct ProjArgs {
    const u16 *MBX, *WC, *QB, *SW;
    const float *biasC, *ZB;
    u16* KGU;
    float* QP;
    const u16 *TXIN, *TXT, *IMIN, *IMT;
    const float *txb, *imb;
    u16 *TXU, *IMU;
};
__global__ __launch_bounds__(256) void proj_kernel(ProjArgs a) {
    int b = blockIdx.x;
    if (b < 200) {
        gemm_body<64, 64, 32, 32, false>(a.MBX, a.WC, a.biasC, a.KGU,
                                         NPOS, HDIM, 2304, b % 8, b / 8, true);
    } else if (b < 225) {
        gemm_body<64, 64, 32, 32, false>(a.QB, a.SW, a.ZB, a.QP,
                                         BATCH, 1600, HDIM, b - 200, 0, false);
    } else if (b < 425) {
        int i = b - 225;
        gemm_body<64, 64, 32, 32, false>(a.TXIN, a.TXT, a.txb, a.TXU,
                                         NPOS, HDIM, TXTD, i % 8, i / 8, true);
    } else {
        int i = b - 425;
        gemm_body<64, 64, 32, 32, false>(a.IMIN, a.IMT, a.imb, a.IMU,
                                         NPOS, HDIM, TXTD, i % 8, i / 8, true);
    }
}

// ---------------------------------------------------------------------------
// 4) tail: fusion + P1 + H fused. 16 rows/block, 100 blocks, 4 waves.
// ---------------------------------------------------------------------------
__global__ __launch_bounds__(256) void tail_kernel(
    const int* __restrict__ eid, const int* __restrict__ map,
    const u16* __restrict__ KGU, const u16* __restrict__ IMU, const u16* __restrict__ TXU,
    const float* __restrict__ qp,
    const u16* __restrict__ W1T, const float* __restrict__ pp1_b1,
    const u16* __restrict__ W2T, const float* __restrict__ pp1_b2,
    u16* __restrict__ Hh) {
    __shared__ u16 FUS[16][520];
    __shared__ u16 P1s[16][264];
    const int bm0 = blockIdx.x * 16;
    const int lane = threadIdx.x & 63;
    const int wv = threadIdx.x >> 6;

    for (int rr = wv; rr < 16; rr += 4) {
        int bl = bm0 + rr;
        int b = bl / ELEN;
        int u = map[eid[bl]];
        const u16* kg = KGU + (size_t)u * HDIM;
        const u16* im = IMU + (size_t)u * HDIM;
        const u16* tx = TXU + (size_t)u * HDIM;
        const float* qrow = qp + (size_t)b * 1600;
        float pkg = 0.f, pim = 0.f, ptx = 0.f;
        for (int e = lane; e < HDIM; e += 64) {
            pkg += bf2f(kg[e]) * qrow[e];
            pim += bf2f(im[e]) * qrow[512 + e];
            ptx += bf2f(tx[e]) * qrow[1024 + e];
        }
        #pragma unroll
        for (int off = 32; off; off >>= 1) {
            pkg += __shfl_down(pkg, off);
            pim += __shfl_down(pim, off);
            ptx += __shfl_down(ptx, off);
        }
        float w0, w1, w2;
        if (lane == 0) {
            float av = pkg + qrow[1536];
            float c1 = pim + qrow[1537];
            float c2 = ptx + qrow[1538];
            float mx = fmaxf(av, fmaxf(c1, c2));
            float ea = __expf(av - mx), eb = __expf(c1 - mx), ec = __expf(c2 - mx);
            float inv = 1.f / (ea + eb + ec);
            w0 = ea * inv; w1 = eb * inv; w2 = ec * inv;
        }
        w0 = __shfl(w0, 0); w1 = __shfl(w1, 0); w2 = __shfl(w2, 0);
        for (int e = lane; e < HDIM; e += 64) {
            float v = w0 * bf2f(kg[e]) + w1 * bf2f(im[e]) + w2 * bf2f(tx[e]);
            FUS[rr][e] = f2bf(v);
        }
    }
    __syncthreads();

    {
        const int rl = lane & 15;
        const int kgrp = lane >> 4;
        f32x4 acc[4];
        #pragma unroll
        for (int j = 0; j < 4; ++j)
            #pragma unroll
            for (int r = 0; r < 4; ++r) acc[j][r] = 0.f;
        for (int kk = 0; kk < 512; kk += 32) {
            int k8 = kk + kgrp * 8;
            bf16x8 af = *(const bf16x8*)&FUS[rl][k8];
            bf16x8 bf[4];
            #pragma unroll
            for (int j = 0; j < 4; ++j) {
                int n = wv * 64 + j * 16 + rl;
                bf[j] = *(const bf16x8*)&W1T[(size_t)n * 512 + k8];
            }
            #pragma unroll
            for (int j = 0; j < 4; ++j)
                acc[j] = __builtin_amdgcn_mfma_f32_16x16x32_bf16(af, bf[j], acc[j], 0, 0, 0);
        }
        const int rg = lane >> 4;
        #pragma unroll
        for (int j = 0; j < 4; ++j) {
            int col = wv * 64 + j * 16 + rl;
            float bv = pp1_b1[col];
            #pragma unroll
            for (int r = 0; r < 4; ++r) {
                int row = rg * 4 + r;
                P1s[row][col] = f2bf(fmaxf(acc[j][r] + bv, 0.f));
            }
        }
    }
    __syncthreads();

    {
        const int rl = lane & 15;
        const int kgrp = lane >> 4;
        f32x4 acc[8];
        #pragma unroll
        for (int j = 0; j < 8; ++j)
            #pragma unroll
            for (int r = 0; r < 4; ++r) acc[j][r] = 0.f;
        for (int kk = 0; kk < 256; kk += 32) {
            int k8 = kk + kgrp * 8;
            bf16x8 af = *(const bf16x8*)&P1s[rl][k8];
            bf16x8 bf[8];
            #pragma unroll
            for (int j = 0; j < 8; ++j) {
                int n = wv * 128 + j * 16 + rl;
                bf[j] = *(const bf16x8*)&W2T[(size_t)n * 256 + k8];
            }
            #pragma unroll
            for (int j = 0; j < 8; ++j)
                acc[j] = __builtin_amdgcn_mfma_f32_16x16x32_bf16(af, bf[j], acc[j], 0, 0, 0);
        }
        const int rg = lane >> 4;
        #pragma unroll
        for (int j = 0; j < 8; ++j) {
            int col = wv * 128 + j * 16 + rl;
            float bv = pp1_b2[col];
            #pragma unroll
            for (int r = 0; r < 4; ++r) {
                int row = rg * 4 + r;
                float v = acc[j][r] + bv + bf2f(FUS[row][col]);
                Hh[(size_t)(bm0 + row) * HDIM + col] = f2bf(v);
            }
        }
    }
}

// ---------------------------------------------------------------------------
// 5) pp2 scatter GEMM
// ---------------------------------------------------------------------------
__global__ __launch_bounds__(256)
void pp2_kernel(const u16* __restrict__ A, const u16* __restrict__ BT,
                const float* __restrict__ bias, void* __restrict__ Cout,
                int M, int N, int K) {
    gemm_body<128, 128, 64, 64, true>(A, BT, bias, Cout, M, N, K, blockIdx.x, blockIdx.y, false);
}

// ---------------------------------------------------------------------------
extern "C" void kernel_launch(void* const* d_in, const int* in_sizes, int n_in,
                              void* d_out, int out_size, void* d_ws, size_t ws_size,
                              hipStream_t stream) {
    const int* entity_ids = (const int*)d_in[0];
    const float* token_embeds = (const float*)d_in[1];
    const int* edge_index = (const int*)d_in[2];
    const int* edge_type = (const int*)d_in[3];
    const float* node_embeds = (const float*)d_in[4];
    const float* rgcn_basis = (const float*)d_in[5];
    const float* rgcn_comp = (const float*)d_in[6];
    const float* rgcn_root = (const float*)d_in[7];
    const float* rgcn_bias = (const float*)d_in[8];
    const float* kg_proj_w = (const float*)d_in[9];
    const float* kg_proj_b = (const float*)d_in[10];
    const float* text_proj_w = (const float*)d_in[11];
    const float* text_proj_b = (const float*)d_in[12];
    const float* image_proj_w = (const float*)d_in[13];
    const float* image_proj_b = (const float*)d_in[14];
    const float* cq_w = (const float*)d_in[15];
    const float* cq_b = (const float*)d_in[16];
    const float* kgk_w = (const float*)d_in[17];
    const float* imk_w = (const float*)d_in[19];
    const float* txk_w = (const float*)d_in[21];
    const float* pp1_w1 = (const float*)d_in[23];
    const float* pp1_b1 = (const float*)d_in[24];
    const float* pp1_w2 = (const float*)d_in[25];
    const float* pp1_b2 = (const float*)d_in[26];
    const float* pp2_w = (const float*)d_in[27];
    const float* pp2_b = (const float*)d_in[28];
    const float* text_init = (const float*)d_in[29];
    const float* image_init = (const float*)d_in[30];

    const int E = in_sizes[3];

    size_t off = 0;
    auto alloc = [&](size_t bytes) { size_t o = off; off += (bytes + 255) & ~(size_t)255; return o; };
    char* ws = (char*)d_ws;
    size_t map_o  = alloc((size_t)NENTS * 4);
    size_t nun_o  = alloc(4);
    size_t unq_o  = alloc((size_t)NPOS * 4);
    size_t scnt_o = alloc((size_t)NSEG * 4);
    size_t bkt_o  = alloc((size_t)NSEG * BCAP * 4);
    size_t mbx_o  = alloc((size_t)NPOS * 2304 * 2);
    size_t w1f_o  = alloc((size_t)2304 * HALF * 2);
    size_t wc_o   = alloc((size_t)HDIM * 2304 * 2);
    size_t bc_o   = alloc((size_t)HDIM * 4);
    size_t kgt_o  = alloc((size_t)HDIM * HALF * 2);
    size_t kgu_o  = alloc((size_t)NPOS * HDIM * 2);
    size_t txin_o = alloc((size_t)NPOS * TXTD * 2);
    size_t imin_o = alloc((size_t)NPOS * TXTD * 2);
    size_t txt_o  = alloc((size_t)HDIM * TXTD * 2);
    size_t imt_o  = alloc((size_t)HDIM * TXTD * 2);
    size_t txu_o  = alloc((size_t)NPOS * HDIM * 2);
    size_t imu_o  = alloc((size_t)NPOS * HDIM * 2);
    size_t tm_o   = alloc((size_t)BATCH * HDIM * 2);
    size_t qb_o   = alloc((size_t)BATCH * HDIM * 2);
    size_t cqt_o  = alloc((size_t)HDIM * HDIM * 2);
    size_t sw_o   = alloc((size_t)1600 * HDIM * 2);
    size_t qp_o   = alloc((size_t)BATCH * 1600 * 4);
    size_t zb_o   = alloc((size_t)2304 * 4);
    size_t w1t_o  = alloc((size_t)HALF * HDIM * 2);
    size_t w2t_o  = alloc((size_t)HDIM * HALF * 2);
    size_t h_o    = alloc((size_t)NPOS * HDIM * 2);
    size_t pp2t_o = alloc((size_t)12288 * HDIM * 2);
    if (off > ws_size) return;

    int* map = (int*)(ws + map_o);
    int* nuniq = (int*)(ws + nun_o);
    int* uniq = (int*)(ws + unq_o);
    int* segcnt = (int*)(ws + scnt_o);
    int* bucket = (int*)(ws + bkt_o);
    u16* MBX = (u16*)(ws + mbx_o);
    u16* W1f = (u16*)(ws + w1f_o);
    u16* WC  = (u16*)(ws + wc_o);
    float* biasC = (float*)(ws + bc_o);
    u16* KGT = (u16*)(ws + kgt_o);
    u16* KGU = (u16*)(ws + kgu_o);
    u16* TXIN = (u16*)(ws + txin_o);
    u16* IMIN = (u16*)(ws + imin_o);
    u16* TXT = (u16*)(ws + txt_o);
    u16* IMT = (u16*)(ws + imt_o);
    u16* TXU = (u16*)(ws + txu_o);
    u16* IMU = (u16*)(ws + imu_o);
    u16* TMEAN = (u16*)(ws + tm_o);
    u16* QB  = (u16*)(ws + qb_o);
    u16* CQT = (u16*)(ws + cqt_o);
    u16* SW  = (u16*)(ws + sw_o);
    float* QP  = (float*)(ws + qp_o);
    float* ZB  = (float*)(ws + zb_o);
    u16* W1T = (u16*)(ws + w1t_o);
    u16* W2T = (u16*)(ws + w2t_o);
    u16* Hh  = (u16*)(ws + h_o);
    u16* PP2T = (u16*)(ws + pp2t_o);
    float* OUT = (float*)d_out;

    // 1) init + dedup fused (blk0 owns map; blk1-2 biasC; blk3-130 zeroing)
    init_kernel<<<131, 256, 0, stream>>>(entity_ids, map, uniq, nuniq, segcnt, ZB,
                                         (const float*)d_in[18], (const float*)d_in[20],
                                         (const float*)d_in[22], SW,
                                         rgcn_bias, kg_proj_w, kg_proj_b, biasC,
                                         OUT + (out_size - 1));
    // 2) midprep (4096 blocks: 64 tokmean | 288 gather | 512 edge-ILP4 | 3232 prep)
    PrepArgs pa;
    pa.src[0] = kg_proj_w;    pa.dst[0] = KGT;
    pa.src[1] = text_proj_w;  pa.dst[1] = TXT;
    pa.src[2] = image_proj_w; pa.dst[2] = IMT;
    pa.src[3] = pp1_w1;       pa.dst[3] = W1T;
    pa.src[4] = pp1_w2;       pa.dst[4] = W2T;
    pa.src[5] = pp2_w;        pa.dst[5] = PP2T;
    pa.src[6] = cq_w;         pa.dst[6] = CQT;
    pa.src[7] = rgcn_basis;   pa.dst[7] = W1f;
    pa.src[8] = rgcn_root;    pa.dst[8] = W1f + (size_t)2048 * HALF;
    pa.src[9] = kgk_w;        pa.dst[9] = SW;
    pa.src[10] = imk_w;       pa.dst[10] = SW + (size_t)HDIM * HDIM;
    pa.src[11] = txk_w;       pa.dst[11] = SW + (size_t)2 * HDIM * HDIM;
    midprep_kernel<<<4096, 256, 0, stream>>>(token_embeds, TMEAN,
                                             uniq, nuniq, text_init, image_init, TXIN, IMIN,
                                             edge_index, edge_type, map, segcnt, bucket, E, pa);
    // 3) build: MBX + QB + WC  (1896 blocks)
    BuildArgs ba;
    ba.segcnt = segcnt; ba.bucket = bucket; ba.uniq = uniq; ba.nuniq = nuniq;
    ba.comp = rgcn_comp; ba.x = node_embeds; ba.MBX = MBX;
    ba.TMEAN = TMEAN; ba.CQT = CQT; ba.cq_b = cq_b; ba.QB = QB;
    ba.KGT = KGT; ba.W1f = W1f; ba.ZB = ZB; ba.WC = WC;
    build_kernel<<<NPOS + 8 + 288, 256, 0, stream>>>(ba);
    // 4) proj: KGU + QP + TXU + IMU  (625 blocks)
    ProjArgs pr;
    pr.MBX = MBX; pr.WC = WC; pr.biasC = biasC; pr.KGU = KGU;
    pr.QB = QB; pr.SW = SW; pr.ZB = ZB; pr.QP = QP;
    pr.TXIN = TXIN; pr.TXT = TXT; pr.IMIN = IMIN; pr.IMT = IMT;
    pr.txb = text_proj_b; pr.imb = image_proj_b; pr.TXU = TXU; pr.IMU = IMU;
    proj_kernel<<<625, 256, 0, stream>>>(pr);
    // 5) tail
    tail_kernel<<<NPOS / 16, 256, 0, stream>>>(entity_ids, map, KGU, IMU, TXU, QP,
                                               W1T, pp1_b1, W2T, pp1_b2, Hh);
    // 6) pp2
    pp2_kernel<<<dim3(12288 / 128, (NPOS + 127) / 128), 256, 0, stream>>>(
        Hh, PP2T, pp2_b, OUT, NPOS, 12288, HDIM);
}

// Round 16
// 149.897 us; speedup vs baseline: 1.0343x; 1.0343x over previous
//
#include <hip/hip_runtime.h>

#define HDIM 512
#define HALF 256
#define NRELS 12
#define NBASES 8
#define NLAYERS 12
#define NBLOCKS 2
#define NHEADS 8
#define NENTS 50000
#define TXTD 768
#define BATCH 32
#define ELEN 50
#define SLEN 128
#define NPOS (BATCH * ELEN)   // 1600
#define NSEG (NPOS * NRELS)   // 19200
#define BCAP 64

typedef unsigned short u16;
typedef __attribute__((ext_vector_type(8))) __bf16 bf16x8;
typedef __attribute__((ext_vector_type(4))) float f32x4;

__device__ __forceinline__ u16 f2bf(float f) {
    unsigned int u = __float_as_uint(f);
    unsigned int r = (u + 0x7FFFu + ((u >> 16) & 1u)) >> 16;
    return (u16)r;
}
__device__ __forceinline__ float bf2f(u16 v) {
    return __uint_as_float(((unsigned int)v) << 16);
}

#define ASYNC_COPY16(g, l)                                                              \
    __builtin_amdgcn_global_load_lds((const __attribute__((address_space(1))) void*)(g), \
                                     (__attribute__((address_space(3))) unsigned int*)(l), 16, 0, 0)

// ---------------------------------------------------------------------------
// 0) init: map=-1, segcnt=0, ZB=0, SW bias rows, biasC = rgcn_bias@kg_proj + kg_b
// ---------------------------------------------------------------------------
__global__ void init_kernel(int* __restrict__ map, int* __restrict__ segcnt,
                            int* __restrict__ nuniq, float* __restrict__ zb,
                            const float* __restrict__ kgb, const float* __restrict__ imb,
                            const float* __restrict__ txb, u16* __restrict__ SW,
                            const float* __restrict__ rgcn_bias,
                            const float* __restrict__ kg_proj_w,
                            const float* __restrict__ kg_proj_b,
                            float* __restrict__ biasC, float* __restrict__ out_last) {
    int blk = blockIdx.x;
    int t = threadIdx.x;
    if (blk >= 128) {
        int n = (blk - 128) * 256 + t;
        float acc = kg_proj_b[n];
        for (int c = 0; c < HALF; ++c) acc += rgcn_bias[c] * kg_proj_w[(size_t)c * HDIM + n];
        biasC[n] = acc;
        return;
    }
    int tid = blk * 256 + t;
    const int nt = 128 * 256;
    int4 m4 = {-1, -1, -1, -1};
    for (int i = tid; i < NENTS / 4; i += nt) ((int4*)map)[i] = m4;
    int4 z4 = {0, 0, 0, 0};
    for (int i = tid; i < NSEG / 4; i += nt) ((int4*)segcnt)[i] = z4;
    for (int i = tid; i < 2304; i += nt) zb[i] = 0.f;
    if (tid < HDIM) {
        SW[(size_t)1536 * HDIM + tid] = f2bf(kgb[tid]);
        SW[(size_t)1537 * HDIM + tid] = f2bf(imb[tid]);
        SW[(size_t)1538 * HDIM + tid] = f2bf(txb[tid]);
    }
    if (tid == 0) { *nuniq = 0; *out_last = 0.f; }
}

// ---------------------------------------------------------------------------
// 1) Dedupe entity ids
// ---------------------------------------------------------------------------
__global__ void dedup_kernel(const int* __restrict__ eid, int* __restrict__ map,
                             int* __restrict__ uniq, int* __restrict__ nuniq) {
    int i = blockIdx.x * blockDim.x + threadIdx.x;
    if (i >= NPOS) return;
    int n = eid[i];
    int old = atomicCAS(&map[n], -1, -2);
    if (old == -1) {
        int idx = atomicAdd(nuniq, 1);
        uniq[idx] = n;
        __threadfence();
        map[n] = idx;
    }
}

// ---------------------------------------------------------------------------
// 2) midprep: {tokmean(64) | gather(288) | edge ILP4(512) | prep(3232)} = 4096
// ---------------------------------------------------------------------------
struct PrepArgs {
    const float* src[12];
    u16* dst[12];
};

__global__ __launch_bounds__(256) void midprep_kernel(
    const float* __restrict__ tok, u16* __restrict__ TMEAN,
    const int* __restrict__ uniq, const int* __restrict__ nuniq,
    const float* __restrict__ txi, const float* __restrict__ imi,
    u16* __restrict__ TXIN, u16* __restrict__ IMIN,
    const int* __restrict__ ei, const int* __restrict__ et, const int* __restrict__ map,
    int* __restrict__ segcnt, int* __restrict__ bucket, int E, PrepArgs a) {
    int blk = blockIdx.x;
    int t = threadIdx.x;
    if (blk < 64) {
        // tokmean
        int b = blk >> 1;
        int col = (blk & 1) * 256 + t;
        float s = 0.f;
        for (int si = 0; si < SLEN; ++si) s += tok[((size_t)b * SLEN + si) * HDIM + col];
        TMEAN[(size_t)b * HDIM + col] = f2bf(s * (1.0f / SLEN));
    } else if (blk < 352) {
        // gather text/image rows
        if (t >= TXTD / 4) return;
        int nu = *nuniq;
        for (int u = blk - 64; u < NPOS; u += 288) {
            if (u >= nu) {
                ushort4 z = {0, 0, 0, 0};
                ((ushort4*)(TXIN + (size_t)u * TXTD))[t] = z;
                ((ushort4*)(IMIN + (size_t)u * TXTD))[t] = z;
                continue;
            }
            int n = uniq[u];
            float4 v = ((const float4*)(txi + (size_t)n * TXTD))[t];
            ushort4 o;
            o.x = f2bf(v.x); o.y = f2bf(v.y); o.z = f2bf(v.z); o.w = f2bf(v.w);
            ((ushort4*)(TXIN + (size_t)u * TXTD))[t] = o;
            v = ((const float4*)(imi + (size_t)n * TXTD))[t];
            o.x = f2bf(v.x); o.y = f2bf(v.y); o.z = f2bf(v.z); o.w = f2bf(v.w);
            ((ushort4*)(IMIN + (size_t)u * TXTD))[t] = o;
        }
    } else if (blk < 864) {
        // edge filter, 4 edges/thread via int4 (independent probe chains)
        const int* __restrict__ dstA = ei + E;
        int gtid = (blk - 352) * 256 + t;
        int e0 = gtid * 4;
        if (e0 + 3 < E) {
            int4 d4 = *(const int4*)(dstA + e0);
            int4 t4 = *(const int4*)(et + e0);
            int cc0 = map[d4.x], cc1 = map[d4.y], cc2 = map[d4.z], cc3 = map[d4.w];
            if (cc0 >= 0) {
                int seg = cc0 * NRELS + t4.x;
                int p = atomicAdd(&segcnt[seg], 1);
                if (p < BCAP) bucket[seg * BCAP + p] = ei[e0];
            }
            if (cc1 >= 0) {
                int seg = cc1 * NRELS + t4.y;
                int p = atomicAdd(&segcnt[seg], 1);
                if (p < BCAP) bucket[seg * BCAP + p] = ei[e0 + 1];
            }
            if (cc2 >= 0) {
                int seg = cc2 * NRELS + t4.z;
                int p = atomicAdd(&segcnt[seg], 1);
                if (p < BCAP) bucket[seg * BCAP + p] = ei[e0 + 2];
            }
            if (cc3 >= 0) {
                int seg = cc3 * NRELS + t4.w;
                int p = atomicAdd(&segcnt[seg], 1);
                if (p < BCAP) bucket[seg * BCAP + p] = ei[e0 + 3];
            }
        } else {
            for (int e = e0; e < E; ++e) {
                int c = map[dstA[e]];
                if (c >= 0) {
                    int seg = c * NRELS + et[e];
                    int p = atomicAdd(&segcnt[seg], 1);
                    if (p < BCAP) bucket[seg * BCAP + p] = ei[e];
                }
            }
        }
    } else {
        // weight prep: 64x64 transposes ops 0-6, straight converts ops 7-11
        // 0:kgproj 1:txproj 2:improj 3:w1 4:w2 5:pp2 6:cq | 7:basis 8:root 9,10,11:score
        constexpr int NN[7]  = {512, 512, 512, 256, 512, 12288, 512};
        constexpr int LDT[7] = {256, 768, 768, 512, 256, 512, 512};
        constexpr int BASE[13] = {0, 32, 128, 224, 256, 288, 1824,
                                  1888, 2400, 2464, 2720, 2976, 3232};
        __shared__ u16 tb[64][65];
        int bid = blk - 864;
        int op = 0;
        #pragma unroll
        for (int i = 1; i < 12; ++i)
            if (bid >= BASE[i]) op = i;
        int idx = bid - BASE[op];
        if (op < 7) {
            int Nv = 0, ldt = 0;
            #pragma unroll
            for (int i = 0; i < 7; ++i)
                if (op == i) { Nv = NN[i]; ldt = LDT[i]; }
            int ncols = Nv >> 6;
            int n0 = (idx % ncols) * 64, k0 = (idx / ncols) * 64;
            const float* W = a.src[op];
            u16* WT = a.dst[op];
            int lane = t & 63, wv = t >> 6;
            #pragma unroll
            for (int i2 = 0; i2 < 16; ++i2) {
                int r = wv * 16 + i2;
                tb[r][lane] = f2bf(W[(size_t)(k0 + r) * Nv + n0 + lane]);
            }
            __syncthreads();
            #pragma unroll
            for (int i2 = 0; i2 < 16; ++i2) {
                int rr = wv * 16 + i2;
                WT[(size_t)(n0 + rr) * ldt + k0 + lane] = tb[lane][rr];
            }
        } else {
            int e = idx * 1024 + t * 4;
            float4 v = *(const float4*)(a.src[op] + e);
            ushort4 o;
            o.x = f2bf(v.x); o.y = f2bf(v.y); o.z = f2bf(v.z); o.w = f2bf(v.w);
            *(ushort4*)(a.dst[op] + e) = o;
        }
    }
}

// ---------------------------------------------------------------------------
// MFMA bf16 GEMM body (outbf runtime) — 4-wave, 64x64, WM=WN=32
// ---------------------------------------------------------------------------
template <int BM, int BN, int WM, int WN, bool SCATTER>
__device__ __forceinline__ void gemm_body(const u16* __restrict__ A, const u16* __restrict__ BT,
                                          const float* __restrict__ bias,
                                          void* __restrict__ Cout, int M, int N, int K,
                                          int bx, int by, bool outbf) {
    constexpr int MF = WM / 16, NF = WN / 16;
    constexpr int NWC = BN / WN;
    __shared__ u16 ldsA[BM][64];
    __shared__ u16 ldsB[BN][64];
    const int tid = threadIdx.x;
    const int lane = tid & 63;
    const int wv = tid >> 6;
    const int m0 = by * BM;
    const int n0 = bx * BN;
    const int wr = wv / NWC, wc = wv % NWC;
    const int srow = lane >> 3;
    const int sslot = lane & 7;

    f32x4 acc[MF][NF];
    #pragma unroll
    for (int i = 0; i < MF; ++i)
        #pragma unroll
        for (int j = 0; j < NF; ++j)
            #pragma unroll
            for (int r = 0; r < 4; ++r) acc[i][j][r] = 0.f;

    for (int k0 = 0; k0 < K; k0 += 64) {
        #pragma unroll
        for (int i = 0; i < BM / 32; ++i) {
            int R = wv * (BM / 4) + i * 8 + srow;
            int gm = m0 + R;
            gm = gm < M ? gm : M - 1;
            int s = sslot ^ (R & 7);
            ASYNC_COPY16(A + (size_t)gm * K + k0 + s * 8, &ldsA[wv * (BM / 4) + i * 8][0]);
        }
        #pragma unroll
        for (int i = 0; i < BN / 32; ++i) {
            int R = wv * (BN / 4) + i * 8 + srow;
            int s = sslot ^ (R & 7);
            ASYNC_COPY16(BT + (size_t)(n0 + R) * K + k0 + s * 8, &ldsB[wv * (BN / 4) + i * 8][0]);
        }
        __syncthreads();
        #pragma unroll
        for (int ks = 0; ks < 2; ++ks) {
            bf16x8 af[MF], bf[NF];
            int kg = ks * 4 + (lane >> 4);
            int rl = lane & 15;
            #pragma unroll
            for (int i = 0; i < MF; ++i) {
                int row = wr * WM + i * 16 + rl;
                af[i] = *(const bf16x8*)&ldsA[row][(kg ^ (row & 7)) * 8];
            }
            #pragma unroll
            for (int j = 0; j < NF; ++j) {
                int row = wc * WN + j * 16 + rl;
                bf[j] = *(const bf16x8*)&ldsB[row][(kg ^ (row & 7)) * 8];
            }
            #pragma unroll
            for (int i = 0; i < MF; ++i)
                #pragma unroll
                for (int j = 0; j < NF; ++j)
                    acc[i][j] = __builtin_amdgcn_mfma_f32_16x16x32_bf16(af[i], bf[j], acc[i][j], 0, 0, 0);
        }
        __syncthreads();
    }

    const int rl = lane & 15, rg = lane >> 4;
    #pragma unroll
    for (int i = 0; i < MF; ++i) {
        #pragma unroll
        for (int j = 0; j < NF; ++j) {
            int col = n0 + wc * WN + j * 16 + rl;
            float bv = bias[col];
            #pragma unroll
            for (int r = 0; r < 4; ++r) {
                int row = m0 + wr * WM + i * 16 + rg * 4 + r;
                if (row >= M) continue;
                float x = acc[i][j][r] + bv;
                if (SCATTER) {
                    int layer = col >> 10, blk = (col >> 9) & 1, head = (col >> 6) & 7, hd = col & 63;
                    int bb = row / ELEN, ll = row - bb * ELEN;
                    size_t oi = (((((size_t)layer * NBLOCKS + blk) * BATCH + bb) * NHEADS + head) * ELEN + ll) * 64 + hd;
                    ((float*)Cout)[oi] = x;
                } else if (outbf) {
                    ((u16*)Cout)[(size_t)row * N + col] = f2bf(x);
                } else {
                    ((float*)Cout)[(size_t)row * N + col] = x;
                }
            }
        }
    }
}

// ---------------------------------------------------------------------------
// 3) build: [0,1600) MBX | [1600,1608) QB | [1608,1896) WC       (1896 blocks)
// ---------------------------------------------------------------------------
struct BuildArgs {
    const int *segcnt, *bucket, *uniq, *nuniq;
    const float *comp, *x;
    u16* MBX;
    const u16 *TMEAN, *CQT;
    const float* cq_b;
    u16* QB;
    const u16 *KGT, *W1f;
    const float* ZB;
    u16* WC;
};
__global__ __launch_bounds__(256) void build_kernel(BuildArgs a) {
    int blk = blockIdx.x;
    if (blk >= NPOS) {
        const u16 *A, *BT;
        const float* bias;
        u16* C;
        int M, N, K, bx, by;
        if (blk >= NPOS + 8) {
            int i = blk - (NPOS + 8);
            A = a.KGT; BT = a.W1f; bias = a.ZB; C = a.WC;
            M = HDIM; N = 2304; K = HALF; bx = i % 36; by = i / 36;
        } else {
            A = a.TMEAN; BT = a.CQT; bias = a.cq_b; C = a.QB;
            M = BATCH; N = HDIM; K = HDIM; bx = blk - NPOS; by = 0;
        }
        gemm_body<64, 64, 32, 32, false>(A, BT, bias, C, M, N, K, bx, by, true);
        return;
    }
    int u = blk;
    int i = threadIdx.x;
    __shared__ float sc[NRELS * NBASES];
    if (i < NRELS * NBASES) sc[i] = a.comp[i];
    __syncthreads();
    u16* row = a.MBX + (size_t)u * 2304;
    int nu = *a.nuniq;
    if (u >= nu) {
        for (int b = 0; b < NBASES + 1; ++b) row[b * HALF + i] = 0;
        return;
    }
    float mr[NRELS];
    #pragma unroll
    for (int r = 0; r < NRELS; ++r) {
        int seg = u * NRELS + r;
        int c = a.segcnt[seg];
        int n = min(c, BCAP);
        float acc = 0.f;
        for (int e = 0; e < n; ++e) {
            int s = a.bucket[seg * BCAP + e];
            acc += a.x[(size_t)s * HALF + i];
        }
        mr[r] = acc * (1.f / fmaxf((float)c, 1.f));
    }
    #pragma unroll
    for (int b = 0; b < NBASES; ++b) {
        float v = 0.f;
        #pragma unroll
        for (int r = 0; r < NRELS; ++r) v += sc[r * NBASES + b] * mr[r];
        row[b * HALF + i] = f2bf(v);
    }
    row[NBASES * HALF + i] = f2bf(a.x[(size_t)a.uniq[u] * HALF + i]);
}

// ---------------------------------------------------------------------------
// 4) proj: {KGU(200) | QP(25) | TXU(200) | IMU(200)} = 625 blocks
// ---------------------------------------------------------------------------
struct ProjArgs {
    const u16 *MBX, *WC, *QB, *SW;
    const float *biasC, *ZB;
    u16* KGU;
    float* QP;
    const u16 *TXIN, *TXT, *IMIN, *IMT;
    const float *txb, *imb;
    u16 *TXU, *IMU;
};
__global__ __launch_bounds__(256) void proj_kernel(ProjArgs a) {
    int b = blockIdx.x;
    if (b < 200) {
        gemm_body<64, 64, 32, 32, false>(a.MBX, a.WC, a.biasC, a.KGU,
                                         NPOS, HDIM, 2304, b % 8, b / 8, true);
    } else if (b < 225) {
        gemm_body<64, 64, 32, 32, false>(a.QB, a.SW, a.ZB, a.QP,
                                         BATCH, 1600, HDIM, b - 200, 0, false);
    } else if (b < 425) {
        int i = b - 225;
        gemm_body<64, 64, 32, 32, false>(a.TXIN, a.TXT, a.txb, a.TXU,
                                         NPOS, HDIM, TXTD, i % 8, i / 8, true);
    } else {
        int i = b - 425;
        gemm_body<64, 64, 32, 32, false>(a.IMIN, a.IMT, a.imb, a.IMU,
                                         NPOS, HDIM, TXTD, i % 8, i / 8, true);
    }
}

// ---------------------------------------------------------------------------
// 5) tail: fusion + P1 + H fused. 16 rows/block, 100 blocks, 4 waves.
// ---------------------------------------------------------------------------
__global__ __launch_bounds__(256) void tail_kernel(
    const int* __restrict__ eid, const int* __restrict__ map,
    const u16* __restrict__ KGU, const u16* __restrict__ IMU, const u16* __restrict__ TXU,
    const float* __restrict__ qp,
    const u16* __restrict__ W1T, const float* __restrict__ pp1_b1,
    const u16* __restrict__ W2T, const float* __restrict__ pp1_b2,
    u16* __restrict__ Hh) {
    __shared__ u16 FUS[16][520];
    __shared__ u16 P1s[16][264];
    const int bm0 = blockIdx.x * 16;
    const int lane = threadIdx.x & 63;
    const int wv = threadIdx.x >> 6;

    for (int rr = wv; rr < 16; rr += 4) {
        int bl = bm0 + rr;
        int b = bl / ELEN;
        int u = map[eid[bl]];
        const u16* kg = KGU + (size_t)u * HDIM;
        const u16* im = IMU + (size_t)u * HDIM;
        const u16* tx = TXU + (size_t)u * HDIM;
        const float* qrow = qp + (size_t)b * 1600;
        float pkg = 0.f, pim = 0.f, ptx = 0.f;
        for (int e = lane; e < HDIM; e += 64) {
            pkg += bf2f(kg[e]) * qrow[e];
            pim += bf2f(im[e]) * qrow[512 + e];
            ptx += bf2f(tx[e]) * qrow[1024 + e];
        }
        #pragma unroll
        for (int off = 32; off; off >>= 1) {
            pkg += __shfl_down(pkg, off);
            pim += __shfl_down(pim, off);
            ptx += __shfl_down(ptx, off);
        }
        float w0, w1, w2;
        if (lane == 0) {
            float av = pkg + qrow[1536];
            float c1 = pim + qrow[1537];
            float c2 = ptx + qrow[1538];
            float mx = fmaxf(av, fmaxf(c1, c2));
            float ea = __expf(av - mx), eb = __expf(c1 - mx), ec = __expf(c2 - mx);
            float inv = 1.f / (ea + eb + ec);
            w0 = ea * inv; w1 = eb * inv; w2 = ec * inv;
        }
        w0 = __shfl(w0, 0); w1 = __shfl(w1, 0); w2 = __shfl(w2, 0);
        for (int e = lane; e < HDIM; e += 64) {
            float v = w0 * bf2f(kg[e]) + w1 * bf2f(im[e]) + w2 * bf2f(tx[e]);
            FUS[rr][e] = f2bf(v);
        }
    }
    __syncthreads();

    {
        const int rl = lane & 15;
        const int kgrp = lane >> 4;
        f32x4 acc[4];
        #pragma unroll
        for (int j = 0; j < 4; ++j)
            #pragma unroll
            for (int r = 0; r < 4; ++r) acc[j][r] = 0.f;
        for (int kk = 0; kk < 512; kk += 32) {
            int k8 = kk + kgrp * 8;
            bf16x8 af = *(const bf16x8*)&FUS[rl][k8];
            bf16x8 bf[4];
            #pragma unroll
            for (int j = 0; j < 4; ++j) {
                int n = wv * 64 + j * 16 + rl;
                bf[j] = *(const bf16x8*)&W1T[(size_t)n * 512 + k8];
            }
            #pragma unroll
            for (int j = 0; j < 4; ++j)
                acc[j] = __builtin_amdgcn_mfma_f32_16x16x32_bf16(af, bf[j], acc[j], 0, 0, 0);
        }
        const int rg = lane >> 4;
        #pragma unroll
        for (int j = 0; j < 4; ++j) {
            int col = wv * 64 + j * 16 + rl;
            float bv = pp1_b1[col];
            #pragma unroll
            for (int r = 0; r < 4; ++r) {
                int row = rg * 4 + r;
                P1s[row][col] = f2bf(fmaxf(acc[j][r] + bv, 0.f));
            }
        }
    }
    __syncthreads();

    {
        const int rl = lane & 15;
        const int kgrp = lane >> 4;
        f32x4 acc[8];
        #pragma unroll
        for (int j = 0; j < 8; ++j)
            #pragma unroll
            for (int r = 0; r < 4; ++r) acc[j][r] = 0.f;
        for (int kk = 0; kk < 256; kk += 32) {
            int k8 = kk + kgrp * 8;
            bf16x8 af = *(const bf16x8*)&P1s[rl][k8];
            bf16x8 bf[8];
            #pragma unroll
            for (int j = 0; j < 8; ++j) {
                int n = wv * 128 + j * 16 + rl;
                bf[j] = *(const bf16x8*)&W2T[(size_t)n * 256 + k8];
            }
            #pragma unroll
            for (int j = 0; j < 8; ++j)
                acc[j] = __builtin_amdgcn_mfma_f32_16x16x32_bf16(af, bf[j], acc[j], 0, 0, 0);
        }
        const int rg = lane >> 4;
        #pragma unroll
        for (int j = 0; j < 8; ++j) {
            int col = wv * 128 + j * 16 + rl;
            float bv = pp1_b2[col];
            #pragma unroll
            for (int r = 0; r < 4; ++r) {
                int row = rg * 4 + r;
                float v = acc[j][r] + bv + bf2f(FUS[row][col]);
                Hh[(size_t)(bm0 + row) * HDIM + col] = f2bf(v);
            }
        }
    }
}

// ---------------------------------------------------------------------------
// 6) pp2 scatter GEMM
// ---------------------------------------------------------------------------
__global__ __launch_bounds__(256)
void pp2_kernel(const u16* __restrict__ A, const u16* __restrict__ BT,
                const float* __restrict__ bias, void* __restrict__ Cout,
                int M, int N, int K) {
    gemm_body<128, 128, 64, 64, true>(A, BT, bias, Cout, M, N, K, blockIdx.x, blockIdx.y, false);
}

// ---------------------------------------------------------------------------
extern "C" void kernel_launch(void* const* d_in, const int* in_sizes, int n_in,
                              void* d_out, int out_size, void* d_ws, size_t ws_size,
                              hipStream_t stream) {
    const int* entity_ids = (const int*)d_in[0];
    const float* token_embeds = (const float*)d_in[1];
    const int* edge_index = (const int*)d_in[2];
    const int* edge_type = (const int*)d_in[3];
    const float* node_embeds = (const float*)d_in[4];
    const float* rgcn_basis = (const float*)d_in[5];
    const float* rgcn_comp = (const float*)d_in[6];
    const float* rgcn_root = (const float*)d_in[7];
    const float* rgcn_bias = (const float*)d_in[8];
    const float* kg_proj_w = (const float*)d_in[9];
    const float* kg_proj_b = (const float*)d_in[10];
    const float* text_proj_w = (const float*)d_in[11];
    const float* text_proj_b = (const float*)d_in[12];
    const float* image_proj_w = (const float*)d_in[13];
    const float* image_proj_b = (const float*)d_in[14];
    const float* cq_w = (const float*)d_in[15];
    const float* cq_b = (const float*)d_in[16];
    const float* kgk_w = (const float*)d_in[17];
    const float* imk_w = (const float*)d_in[19];
    const float* txk_w = (const float*)d_in[21];
    const float* pp1_w1 = (const float*)d_in[23];
    const float* pp1_b1 = (const float*)d_in[24];
    const float* pp1_w2 = (const float*)d_in[25];
    const float* pp1_b2 = (const float*)d_in[26];
    const float* pp2_w = (const float*)d_in[27];
    const float* pp2_b = (const float*)d_in[28];
    const float* text_init = (const float*)d_in[29];
    const float* image_init = (const float*)d_in[30];

    const int E = in_sizes[3];

    size_t off = 0;
    auto alloc = [&](size_t bytes) { size_t o = off; off += (bytes + 255) & ~(size_t)255; return o; };
    char* ws = (char*)d_ws;
    size_t map_o  = alloc((size_t)NENTS * 4);
    size_t nun_o  = alloc(4);
    size_t unq_o  = alloc((size_t)NPOS * 4);
    size_t scnt_o = alloc((size_t)NSEG * 4);
    size_t bkt_o  = alloc((size_t)NSEG * BCAP * 4);
    size_t mbx_o  = alloc((size_t)NPOS * 2304 * 2);
    size_t w1f_o  = alloc((size_t)2304 * HALF * 2);
    size_t wc_o   = alloc((size_t)HDIM * 2304 * 2);
    size_t bc_o   = alloc((size_t)HDIM * 4);
    size_t kgt_o  = alloc((size_t)HDIM * HALF * 2);
    size_t kgu_o  = alloc((size_t)NPOS * HDIM * 2);
    size_t txin_o = alloc((size_t)NPOS * TXTD * 2);
    size_t imin_o = alloc((size_t)NPOS * TXTD * 2);
    size_t txt_o  = alloc((size_t)HDIM * TXTD * 2);
    size_t imt_o  = alloc((size_t)HDIM * TXTD * 2);
    size_t txu_o  = alloc((size_t)NPOS * HDIM * 2);
    size_t imu_o  = alloc((size_t)NPOS * HDIM * 2);
    size_t tm_o   = alloc((size_t)BATCH * HDIM * 2);
    size_t qb_o   = alloc((size_t)BATCH * HDIM * 2);
    size_t cqt_o  = alloc((size_t)HDIM * HDIM * 2);
    size_t sw_o   = alloc((size_t)1600 * HDIM * 2);
    size_t qp_o   = alloc((size_t)BATCH * 1600 * 4);
    size_t zb_o   = alloc((size_t)2304 * 4);
    size_t w1t_o  = alloc((size_t)HALF * HDIM * 2);
    size_t w2t_o  = alloc((size_t)HDIM * HALF * 2);
    size_t h_o    = alloc((size_t)NPOS * HDIM * 2);
    size_t pp2t_o = alloc((size_t)12288 * HDIM * 2);
    if (off > ws_size) return;

    int* map = (int*)(ws + map_o);
    int* nuniq = (int*)(ws + nun_o);
    int* uniq = (int*)(ws + unq_o);
    int* segcnt = (int*)(ws + scnt_o);
    int* bucket = (int*)(ws + bkt_o);
    u16* MBX = (u16*)(ws + mbx_o);
    u16* W1f = (u16*)(ws + w1f_o);
    u16* WC  = (u16*)(ws + wc_o);
    float* biasC = (float*)(ws + bc_o);
    u16* KGT = (u16*)(ws + kgt_o);
    u16* KGU = (u16*)(ws + kgu_o);
    u16* TXIN = (u16*)(ws + txin_o);
    u16* IMIN = (u16*)(ws + imin_o);
    u16* TXT = (u16*)(ws + txt_o);
    u16* IMT = (u16*)(ws + imt_o);
    u16* TXU = (u16*)(ws + txu_o);
    u16* IMU = (u16*)(ws + imu_o);
    u16* TMEAN = (u16*)(ws + tm_o);
    u16* QB  = (u16*)(ws + qb_o);
    u16* CQT = (u16*)(ws + cqt_o);
    u16* SW  = (u16*)(ws + sw_o);
    float* QP  = (float*)(ws + qp_o);
    float* ZB  = (float*)(ws + zb_o);
    u16* W1T = (u16*)(ws + w1t_o);
    u16* W2T = (u16*)(ws + w2t_o);
    u16* Hh  = (u16*)(ws + h_o);
    u16* PP2T = (u16*)(ws + pp2t_o);
    float* OUT = (float*)d_out;

    // 1) init
    init_kernel<<<130, 256, 0, stream>>>(map, segcnt, nuniq, ZB,
                                         (const float*)d_in[18], (const float*)d_in[20],
                                         (const float*)d_in[22], SW,
                                         rgcn_bias, kg_proj_w, kg_proj_b, biasC,
                                         OUT + (out_size - 1));
    // 2) dedup
    dedup_kernel<<<(NPOS + 255) / 256, 256, 0, stream>>>(entity_ids, map, uniq, nuniq);
    // 3) midprep (4096 blocks: 64 tokmean | 288 gather | 512 edge-ILP4 | 3232 prep)
    PrepArgs pa;
    pa.src[0] = kg_proj_w;    pa.dst[0] = KGT;
    pa.src[1] = text_proj_w;  pa.dst[1] = TXT;
    pa.src[2] = image_proj_w; pa.dst[2] = IMT;
    pa.src[3] = pp1_w1;       pa.dst[3] = W1T;
    pa.src[4] = pp1_w2;       pa.dst[4] = W2T;
    pa.src[5] = pp2_w;        pa.dst[5] = PP2T;
    pa.src[6] = cq_w;         pa.dst[6] = CQT;
    pa.src[7] = rgcn_basis;   pa.dst[7] = W1f;
    pa.src[8] = rgcn_root;    pa.dst[8] = W1f + (size_t)2048 * HALF;
    pa.src[9] = kgk_w;        pa.dst[9] = SW;
    pa.src[10] = imk_w;       pa.dst[10] = SW + (size_t)HDIM * HDIM;
    pa.src[11] = txk_w;       pa.dst[11] = SW + (size_t)2 * HDIM * HDIM;
    midprep_kernel<<<4096, 256, 0, stream>>>(token_embeds, TMEAN,
                                             uniq, nuniq, text_init, image_init, TXIN, IMIN,
                                             edge_index, edge_type, map, segcnt, bucket, E, pa);
    // 4) build: MBX + QB + WC  (1896 blocks)
    BuildArgs ba;
    ba.segcnt = segcnt; ba.bucket = bucket; ba.uniq = uniq; ba.nuniq = nuniq;
    ba.comp = rgcn_comp; ba.x = node_embeds; ba.MBX = MBX;
    ba.TMEAN = TMEAN; ba.CQT = CQT; ba.cq_b = cq_b; ba.QB = QB;
    ba.KGT = KGT; ba.W1f = W1f; ba.ZB = ZB; ba.WC = WC;
    build_kernel<<<NPOS + 8 + 288, 256, 0, stream>>>(ba);
    // 5) proj: KGU + QP + TXU + IMU  (625 blocks)
    ProjArgs pr;
    pr.MBX = MBX; pr.WC = WC; pr.biasC = biasC; pr.KGU = KGU;
    pr.QB = QB; pr.SW = SW; pr.ZB = ZB; pr.QP = QP;
    pr.TXIN = TXIN; pr.TXT = TXT; pr.IMIN = IMIN; pr.IMT = IMT;
    pr.txb = text_proj_b; pr.imb = image_proj_b; pr.TXU = TXU; pr.IMU = IMU;
    proj_kernel<<<625, 256, 0, stream>>>(pr);
    // 6) tail
    tail_kernel<<<NPOS / 16, 256, 0, stream>>>(entity_ids, map, KGU, IMU, TXU, QP,
                                               W1T, pp1_b1, W2T, pp1_b2, Hh);
    // 7) pp2
    pp2_kernel<<<dim3(12288 / 128, (NPOS + 127) / 128), 256, 0, stream>>>(
        Hh, PP2T, pp2_b, OUT, NPOS, 12288, HDIM);
}